// Round 3
// baseline (257.816 us; speedup 1.0000x reference)
//
#include <hip/hip_runtime.h>
#include <hip/hip_bf16.h>

#define NN 8192
#define FIN 128
#define FOUT 64
#define KSPLIT 8
#define KCH (NN / KSPLIT)     // 1024
#define KSTEPS (KCH / 64)     // 16
#define NB (NN / 8)           // 1024 mask bytes per row

typedef __attribute__((ext_vector_type(8))) short short8;
typedef __attribute__((ext_vector_type(4))) float f32x4;
typedef unsigned int u32;
typedef unsigned char u8;
typedef unsigned long long u64;

static __device__ __forceinline__ short f2bf(float f) {
    union { __hip_bfloat16 h; short s; } u;
    u.h = __float2bfloat16(f);
    return u.s;
}
static __device__ __forceinline__ float bf2f(short s) {
    union { __hip_bfloat16 h; short s; } u;
    u.s = s;
    return __bfloat162float(u.h);
}

// byte (8 mask bits) -> 8 bf16 values {0,1} packed as short8
static __device__ __forceinline__ short8 expand8(u32 b) {
    u32 xl = ((b & 0xFu) * 0x00204081u) & 0x01010101u;         // bytes = bits 0..3
    u32 xh = (((b >> 4) & 0xFu) * 0x00204081u) & 0x01010101u;  // bytes = bits 4..7
    u32 d0 = __builtin_amdgcn_perm(0u, xl, 0x0C010C00u) * 0x3F80u;
    u32 d1 = __builtin_amdgcn_perm(0u, xl, 0x0C030C02u) * 0x3F80u;
    u32 d2 = __builtin_amdgcn_perm(0u, xh, 0x0C010C00u) * 0x3F80u;
    u32 d3 = __builtin_amdgcn_perm(0u, xh, 0x0C030C02u) * 0x3F80u;
    union { u32 u[4]; short8 v; } r;
    r.u[0] = d0; r.u[1] = d1; r.u[2] = d2; r.u[3] = d3;
    return r.v;
}

// ---------- A (fp32 0/1) -> byte mask, lane-local pack, no ballot ----------
__global__ __launch_bounds__(256) void mask_kernel(const float* __restrict__ A,
                                                   u8* __restrict__ m8) {
    const int row = blockIdx.x * 4 + (threadIdx.x >> 6);
    const int l = threadIdx.x & 63;
    const float* ar = A + (size_t)row * NN + l * 8;
    u8* mr = m8 + (size_t)row * NB + l;
    #pragma unroll 2
    for (int kc = 0; kc < NN; kc += 512) {
        float4 a = *(const float4*)(ar + kc);
        float4 b = *(const float4*)(ar + kc + 4);
        u32 x0 = __float_as_uint(a.x), x1 = __float_as_uint(a.y);
        u32 x2 = __float_as_uint(a.z), x3 = __float_as_uint(a.w);
        u32 x4 = __float_as_uint(b.x), x5 = __float_as_uint(b.y);
        u32 x6 = __float_as_uint(b.z), x7 = __float_as_uint(b.w);
        // collect byte3 of each float: 0x3F if 1.0f else 0
        u32 ylo = __builtin_amdgcn_perm(x1, x0, 0x0C0C0703u) |
                  __builtin_amdgcn_perm(x3, x2, 0x07030C0Cu);
        u32 yhi = __builtin_amdgcn_perm(x5, x4, 0x0C0C0703u) |
                  __builtin_amdgcn_perm(x7, x6, 0x07030C0Cu);
        u32 nlo = (((ylo >> 5) & 0x01010101u) * 0x01020408u) >> 24;
        u32 nhi = (((yhi >> 5) & 0x01010101u) * 0x01020408u) >> 24;
        mr[kc >> 3] = (u8)(nlo | (nhi << 4));
    }
}

// ---------- XW = X @ W + bias, transposed bf16 hi/lo [FOUT][NN] ----------
__global__ __launch_bounds__(256) void xw_kernel(const float* __restrict__ X,
        const float* __restrict__ W, const float* __restrict__ bias,
        short* __restrict__ XWhi, short* __restrict__ XWlo) {
    __shared__ float Xs[64][FIN + 1];
    const int t = threadIdx.x;
    const int jb = blockIdx.x * 64;
    for (int u = t; u < 64 * FIN; u += 256) {
        int r = u >> 7, k = u & (FIN - 1);
        Xs[r][k] = X[(size_t)(jb + r) * FIN + k];
    }
    __syncthreads();
    const int j = t & 63;
    const int cg = t >> 6;
    float acc[16];
    #pragma unroll
    for (int q = 0; q < 16; ++q) acc[q] = bias[cg * 16 + q];
    for (int k = 0; k < FIN; ++k) {
        float x = Xs[j][k];
        #pragma unroll
        for (int q = 0; q < 16; ++q)
            acc[q] = fmaf(x, W[k * FOUT + cg * 16 + q], acc[q]);
    }
    #pragma unroll
    for (int q = 0; q < 16; ++q) {
        int c = cg * 16 + q;
        float v = acc[q];
        short hi = f2bf(v);
        float lo = v - bf2f(hi);
        XWhi[(size_t)c * NN + jb + j] = hi;
        XWlo[(size_t)c * NN + jb + j] = f2bf(lo);
    }
}

// ---------- pass 1: agg partials = mask @ XW (hi+lo), A-frags from mask bytes ----------
__global__ __launch_bounds__(256, 4) void mm1_kernel(const u8* __restrict__ m8,
        const short* __restrict__ Bhi, const short* __restrict__ Blo,
        float* __restrict__ aggp) {
    __shared__ short Bs[2][2][4096];   // [dbuf][hi/lo][64c x 64k], XOR-swizzled
    const int t = threadIdx.x;
    const int mt = blockIdx.x, ks = blockIdx.y;
    const int l = t & 63, w = t >> 6;
    const int fr = l & 15, fg = l >> 4;
    const int r_row = mt * 64 + w * 16 + fr;
    const int kbase = ks * KCH;
    const u8* mrow = m8 + (size_t)r_row * NB;

    f32x4 acc[4] = {};
    short8 sh[2], sl[2];

    auto LOADSTG = [&](int k0) {
        #pragma unroll
        for (int r = 0; r < 2; ++r) {
            int idx = t + 256 * r;
            int c = idx >> 3;
            int kk = ((idx & 7) ^ (c & 7)) * 8;
            size_t g = (size_t)c * NN + k0 + kk;
            sh[r] = *(const short8*)(Bhi + g);
            sl[r] = *(const short8*)(Blo + g);
        }
    };
    auto WRITESTG = [&](int buf) {
        #pragma unroll
        for (int r = 0; r < 2; ++r) {
            int idx = t + 256 * r;
            *(short8*)&Bs[buf][0][idx * 8] = sh[r];
            *(short8*)&Bs[buf][1][idx * 8] = sl[r];
        }
    };

    LOADSTG(kbase);
    WRITESTG(0);
    LOADSTG(kbase + 64);
    __syncthreads();

    int cur = 0;
    for (int kt = 0; kt < KSTEPS; ++kt) {
        const int k0 = kbase + kt * 64;
        const int nxt = cur ^ 1;
        if (kt + 1 < KSTEPS) WRITESTG(nxt);       // tile kt+1 -> other buffer
        if (kt + 2 < KSTEPS) LOADSTG(k0 + 128);   // prefetch tile kt+2
        u64 mw = *(const u64*)(mrow + (k0 >> 3));
        short8 a0 = expand8((u32)(mw >> (fg * 8)) & 0xFFu);
        short8 a1 = expand8((u32)(mw >> (fg * 8 + 32)) & 0xFFu);
        #pragma unroll
        for (int n = 0; n < 4; ++n) {
            const int c = n * 16 + fr;
            const int cs = (c & 7) << 4;
            #pragma unroll
            for (int h = 0; h < 2; ++h) {
                int off = (c * 128 + ((h * 64 + fg * 16) ^ cs)) >> 1;
                short8 bh = *(const short8*)&Bs[cur][0][off];
                short8 bl = *(const short8*)&Bs[cur][1][off];
                short8 af = h ? a1 : a0;
                acc[n] = __builtin_amdgcn_mfma_f32_16x16x32_bf16(af, bh, acc[n], 0, 0, 0);
                acc[n] = __builtin_amdgcn_mfma_f32_16x16x32_bf16(af, bl, acc[n], 0, 0, 0);
            }
        }
        __syncthreads();
        cur = nxt;
    }

    const int i0 = mt * 64 + w * 16 + fg * 4;
    #pragma unroll
    for (int n = 0; n < 4; ++n) {
        const int c = n * 16 + fr;
        *(float4*)&aggp[((size_t)ks * FOUT + c) * NN + i0] = *(float4*)&acc[n];
    }
}

// ---------- fused split-K reduce + sj + per-block max ----------
__global__ __launch_bounds__(256) void sjred_kernel(const float* __restrict__ aggp,
        const float* __restrict__ phi, float* __restrict__ aggr,
        float* __restrict__ sjv, float* __restrict__ maxp) {
    const int i = blockIdx.x * 256 + threadIdx.x;
    float s = 0.f;
    #pragma unroll 8
    for (int c = 0; c < FOUT; ++c) {
        float v = 0.f;
        #pragma unroll
        for (int ksp = 0; ksp < KSPLIT; ++ksp)
            v += aggp[((size_t)ksp * FOUT + c) * NN + i];
        aggr[(size_t)c * NN + i] = v;
        s += v * phi[FOUT + c];
    }
    sjv[i] = s;
    float m = s;
    #pragma unroll
    for (int o = 32; o >= 1; o >>= 1) m = fmaxf(m, __shfl_down(m, o, 64));
    __shared__ float red[4];
    if ((threadIdx.x & 63) == 0) red[threadIdx.x >> 6] = m;
    __syncthreads();
    if (threadIdx.x == 0)
        maxp[blockIdx.x] = fmaxf(fmaxf(red[0], red[1]), fmaxf(red[2], red[3]));
}

__global__ void maxfin_kernel(const float* __restrict__ maxp, float* __restrict__ Mb) {
    int t = threadIdx.x;
    float m = t < 32 ? maxp[t] : -3.0e38f;
    #pragma unroll
    for (int o = 32; o >= 1; o >>= 1) m = fmaxf(m, __shfl_down(m, o, 64));
    if (t == 0) Mb[0] = m;
}

// ---------- B2[c][j]: c<64 -> e_j*aggr[c][j]; c==64 -> e_j; else 0 (bf16) ----------
__global__ __launch_bounds__(256) void bbuild_kernel(const float* __restrict__ aggr,
        const float* __restrict__ sjv, const float* __restrict__ Mb,
        short* __restrict__ B2) {
    int idx = blockIdx.x * 256 + threadIdx.x;
    int c = idx >> 13;
    int j = idx & (NN - 1);
    float e = __expf(sjv[j] - Mb[0]);
    float x;
    if (c < FOUT)       x = aggr[(size_t)c * NN + j] * e;
    else if (c == FOUT) x = e;
    else                x = 0.f;
    B2[idx] = f2bf(x);
}

// ---------- pass 2: h partials = (mask+I) @ B2 (single bf16), 80 cols ----------
__global__ __launch_bounds__(256, 4) void mm2_kernel(const u8* __restrict__ m8,
        const short* __restrict__ B2, float* __restrict__ hp) {
    __shared__ short Bs[2][5120];      // [dbuf][80c x 64k]
    const int t = threadIdx.x;
    const int mt = blockIdx.x, ks = blockIdx.y;
    const int l = t & 63, w = t >> 6;
    const int fr = l & 15, fg = l >> 4;
    const int r_row = mt * 64 + w * 16 + fr;
    const int kbase = ks * KCH;
    const u8* mrow = m8 + (size_t)r_row * NB;

    f32x4 acc[5] = {};
    short8 s2[3];

    auto LOADSTG = [&](int k0) {
        #pragma unroll
        for (int r = 0; r < 3; ++r) {
            int idx = t + 256 * r;
            if (idx < 640) {
                int c = idx >> 3;
                int kk = ((idx & 7) ^ (c & 7)) * 8;
                s2[r] = *(const short8*)(B2 + (size_t)c * NN + k0 + kk);
            }
        }
    };
    auto WRITESTG = [&](int buf) {
        #pragma unroll
        for (int r = 0; r < 3; ++r) {
            int idx = t + 256 * r;
            if (idx < 640) *(short8*)&Bs[buf][idx * 8] = s2[r];
        }
    };

    LOADSTG(kbase);
    WRITESTG(0);
    LOADSTG(kbase + 64);
    __syncthreads();

    int cur = 0;
    for (int kt = 0; kt < KSTEPS; ++kt) {
        const int k0 = kbase + kt * 64;
        const int nxt = cur ^ 1;
        if (kt + 1 < KSTEPS) WRITESTG(nxt);
        if (kt + 2 < KSTEPS) LOADSTG(k0 + 128);
        u64 mw = *(const u64*)(mrow + (k0 >> 3));
        u32 b0 = (u32)(mw >> (fg * 8)) & 0xFFu;
        u32 b1 = (u32)(mw >> (fg * 8 + 32)) & 0xFFu;
        u32 d0 = (u32)(r_row - (k0 + fg * 8));
        u32 d1 = (u32)(r_row - (k0 + 32 + fg * 8));
        if (d0 < 8u) b0 |= 1u << d0;          // +I diagonal
        if (d1 < 8u) b1 |= 1u << d1;
        short8 a0 = expand8(b0);
        short8 a1 = expand8(b1);
        #pragma unroll
        for (int n = 0; n < 5; ++n) {
            const int c = n * 16 + fr;
            const int cs = (c & 7) << 4;
            #pragma unroll
            for (int h = 0; h < 2; ++h) {
                int off = (c * 128 + ((h * 64 + fg * 16) ^ cs)) >> 1;
                short8 bb = *(const short8*)&Bs[cur][off];
                short8 af = h ? a1 : a0;
                acc[n] = __builtin_amdgcn_mfma_f32_16x16x32_bf16(af, bb, acc[n], 0, 0, 0);
            }
        }
        __syncthreads();
        cur = nxt;
    }

    const int i0 = mt * 64 + w * 16 + fg * 4;
    #pragma unroll
    for (int n = 0; n < 5; ++n) {
        const int c = n * 16 + fr;
        #pragma unroll
        for (int q = 0; q < 4; ++q)
            hp[((size_t)ks * NN + i0 + q) * 80 + c] = acc[n][q];
    }
}

// ---------- out = relu(num/den) over split-K partials ----------
__global__ __launch_bounds__(256) void final_kernel(const float* __restrict__ hp,
                                                    float* __restrict__ out) {
    int idx = blockIdx.x * 256 + threadIdx.x;
    int i = idx >> 6, c = idx & 63;
    float num = 0.f, den = 0.f;
    #pragma unroll
    for (int ksp = 0; ksp < KSPLIT; ++ksp) {
        num += hp[((size_t)ksp * NN + i) * 80 + c];
        den += hp[((size_t)ksp * NN + i) * 80 + 64];
    }
    float v = num / den;
    out[idx] = v > 0.f ? v : 0.f;
}

extern "C" void kernel_launch(void* const* d_in, const int* in_sizes, int n_in,
                              void* d_out, int out_size, void* d_ws, size_t ws_size,
                              hipStream_t stream) {
    const float* A    = (const float*)d_in[0];
    const float* X    = (const float*)d_in[1];
    const float* W    = (const float*)d_in[2];
    const float* bias = (const float*)d_in[3];
    const float* phi  = (const float*)d_in[4];
    float* out = (float*)d_out;

    char* ws = (char*)d_ws;
    size_t off = 0;
    auto alloc = [&](size_t bytes) -> void* {
        void* p = ws + off;
        off += (bytes + 255) & ~(size_t)255;
        return p;
    };
    u8*    m8   = (u8*)alloc((size_t)NN * NB);
    short* XWhi = (short*)alloc((size_t)FOUT * NN * 2);
    short* XWlo = (short*)alloc((size_t)FOUT * NN * 2);
    float* aggp = (float*)alloc((size_t)KSPLIT * FOUT * NN * 4);
    float* aggr = (float*)alloc((size_t)FOUT * NN * 4);
    float* sjv  = (float*)alloc((size_t)NN * 4);
    float* maxp = (float*)alloc(32 * 4);
    float* Mb   = (float*)alloc(256);
    short* B2   = (short*)alloc((size_t)80 * NN * 2);
    float* hp   = (float*)alloc((size_t)KSPLIT * NN * 80 * 4);

    mask_kernel<<<NN / 4, 256, 0, stream>>>(A, m8);
    xw_kernel<<<NN / 64, 256, 0, stream>>>(X, W, bias, XWhi, XWlo);
    mm1_kernel<<<dim3(NN / 64, KSPLIT), 256, 0, stream>>>(m8, XWhi, XWlo, aggp);
    sjred_kernel<<<NN / 256, 256, 0, stream>>>(aggp, phi, aggr, sjv, maxp);
    maxfin_kernel<<<1, 64, 0, stream>>>(maxp, Mb);
    bbuild_kernel<<<80 * NN / 256, 256, 0, stream>>>(aggr, sjv, Mb, B2);
    mm2_kernel<<<dim3(NN / 64, KSPLIT), 256, 0, stream>>>(m8, B2, hp);
    final_kernel<<<NN * 64 / 256, 256, 0, stream>>>(hp, out);
}

// Round 4
// 176.365 us; speedup vs baseline: 1.4618x; 1.4618x over previous
//
#include <hip/hip_runtime.h>
#include <hip/hip_bf16.h>

#define NN 8192
#define FIN 128
#define FOUT 64
#define KSPLIT 16
#define KCH (NN / KSPLIT)    // 512
#define KT_PER (KCH / 16)    // 32 k-tiles of 16 per block
#define NWRD (NN / 64)       // 128 u64 words per mask row
#define NB (NN / 8)          // 1024 mask bytes per row

typedef __attribute__((ext_vector_type(8))) short short8;
typedef __attribute__((ext_vector_type(16))) float f32x16;
typedef unsigned int u32;
typedef unsigned char u8;
typedef unsigned long long u64;

static __device__ __forceinline__ short f2bf(float f) {
    union { __hip_bfloat16 h; short s; } u;
    u.h = __float2bfloat16(f);
    return u.s;
}

// one mask byte (8 bits) -> 8 bf16 {0,1.0} packed in short8
static __device__ __forceinline__ short8 expand8(u32 b) {
    u32 xl = ((b & 0xFu) * 0x00204081u) & 0x01010101u;
    u32 xh = (((b >> 4) & 0xFu) * 0x00204081u) & 0x01010101u;
    u32 d0 = __builtin_amdgcn_perm(0u, xl, 0x0C010C00u) * 0x3F80u;
    u32 d1 = __builtin_amdgcn_perm(0u, xl, 0x0C030C02u) * 0x3F80u;
    u32 d2 = __builtin_amdgcn_perm(0u, xh, 0x0C010C00u) * 0x3F80u;
    u32 d3 = __builtin_amdgcn_perm(0u, xh, 0x0C030C02u) * 0x3F80u;
    union { u32 u[4]; short8 v; } r;
    r.u[0] = d0; r.u[1] = d1; r.u[2] = d2; r.u[3] = d3;
    return r.v;
}

// ---------- XW (no bias) -> fragment-major bf16 + y = XW@phi_j + cb ----------
__global__ __launch_bounds__(256) void xw_kernel(const float* __restrict__ X,
        const float* __restrict__ W, const float* __restrict__ bias,
        const float* __restrict__ phi, short* __restrict__ XWf,
        float* __restrict__ y, float* __restrict__ cb) {
    __shared__ float Xs[64][FIN + 1];
    __shared__ short T[64][72];     // [node j][col c] bf16, padded
    __shared__ float yp[4][64];
    const int t = threadIdx.x;
    const int jb = blockIdx.x * 64;
    for (int u = t; u < 64 * FIN; u += 256) {
        int r = u >> 7, k = u & (FIN - 1);
        Xs[r][k] = X[(size_t)(jb + r) * FIN + k];
    }
    __syncthreads();
    const int j = t & 63;
    const int cg = t >> 6;
    float acc[16] = {};
    for (int k = 0; k < FIN; ++k) {
        float x = Xs[j][k];
        #pragma unroll
        for (int q = 0; q < 16; ++q)
            acc[q] = fmaf(x, W[k * FOUT + cg * 16 + q], acc[q]);
    }
    float ys = 0.f;
    union { short s[16]; short8 v[2]; } pk;
    #pragma unroll
    for (int q = 0; q < 16; ++q) {
        ys = fmaf(acc[q], phi[FOUT + cg * 16 + q], ys);
        pk.s[q] = f2bf(acc[q]);
    }
    *(short8*)&T[j][cg * 16] = pk.v[0];
    *(short8*)&T[j][cg * 16 + 8] = pk.v[1];
    yp[cg][j] = ys;
    __syncthreads();
    if (t < 64) y[jb + t] = yp[0][t] + yp[1][t] + yp[2][t] + yp[3][t];
    if (blockIdx.x == 0 && t == 0) {
        float s = 0.f;
        for (int c = 0; c < FOUT; ++c) s = fmaf(bias[c], phi[FOUT + c], s);
        cb[0] = s;
    }
    // fragment-major write: frag covers 32 cols x 16 k-nodes
    #pragma unroll
    for (int uu = 0; uu < 2; ++uu) {
        int u = t + uu * 256;
        int f = u >> 6, ln = u & 63;
        int c = (f & 1) * 32 + (ln & 31);
        int j0 = (f >> 1) * 16 + (ln >> 5) * 8;
        union { short s[8]; short8 v; } w8;
        #pragma unroll
        for (int e = 0; e < 8; ++e) w8.s[e] = T[j0 + e][c];
        size_t fg = ((size_t)(jb >> 4) + (f >> 1)) * 2 + (f & 1);
        *(short8*)&XWf[fg * 512 + ln * 8] = w8.v;
    }
}

// ---------- A -> bitmask bytes; fused exact sj_i = A@y + cb; block max ----------
__global__ __launch_bounds__(256) void mask_kernel(const float* __restrict__ A,
        const float* __restrict__ y, const float* __restrict__ cb,
        u8* __restrict__ m8, float* __restrict__ sjv, float* __restrict__ maxp) {
    __shared__ float4 ys4[NN / 4];
    const float* ysp = (const float*)ys4;
    for (int i = threadIdx.x; i < NN / 4; i += 256)
        ys4[i] = ((const float4*)y)[i];
    __syncthreads();
    const int t = threadIdx.x;
    const int row = blockIdx.x * 4 + (t >> 6);
    const int l = t & 63;
    const float* ar = A + (size_t)row * NN + l * 8;
    u8* mr = m8 + (size_t)row * NB + l;
    float s = 0.f;
    #pragma unroll 2
    for (int kc = 0; kc < NN; kc += 512) {
        float4 a = *(const float4*)(ar + kc);
        float4 b = *(const float4*)(ar + kc + 4);
        float4 y0 = *(const float4*)(ysp + kc + l * 8);
        float4 y1 = *(const float4*)(ysp + kc + l * 8 + 4);
        s = fmaf(a.x, y0.x, s); s = fmaf(a.y, y0.y, s);
        s = fmaf(a.z, y0.z, s); s = fmaf(a.w, y0.w, s);
        s = fmaf(b.x, y1.x, s); s = fmaf(b.y, y1.y, s);
        s = fmaf(b.z, y1.z, s); s = fmaf(b.w, y1.w, s);
        u32 x0 = __float_as_uint(a.x), x1 = __float_as_uint(a.y);
        u32 x2 = __float_as_uint(a.z), x3 = __float_as_uint(a.w);
        u32 x4 = __float_as_uint(b.x), x5 = __float_as_uint(b.y);
        u32 x6 = __float_as_uint(b.z), x7 = __float_as_uint(b.w);
        u32 ylo = __builtin_amdgcn_perm(x1, x0, 0x0C0C0703u) |
                  __builtin_amdgcn_perm(x3, x2, 0x07030C0Cu);
        u32 yhi = __builtin_amdgcn_perm(x5, x4, 0x0C0C0703u) |
                  __builtin_amdgcn_perm(x7, x6, 0x07030C0Cu);
        u32 nlo = (((ylo >> 5) & 0x01010101u) * 0x01020408u) >> 24;
        u32 nhi = (((yhi >> 5) & 0x01010101u) * 0x01020408u) >> 24;
        mr[kc >> 3] = (u8)(nlo | (nhi << 4));
    }
    #pragma unroll
    for (int o = 32; o >= 1; o >>= 1) s += __shfl_down(s, o, 64);
    __shared__ float red[4];
    float sj = s + cb[0];
    if (l == 0) { sjv[row] = sj; red[t >> 6] = sj; }
    __syncthreads();
    if (t == 0)
        maxp[blockIdx.x] = fmaxf(fmaxf(red[0], red[1]), fmaxf(red[2], red[3]));
}

__global__ __launch_bounds__(256) void maxfin_kernel(const float* __restrict__ maxp,
                                                     float* __restrict__ Mb) {
    float m = -3.0e38f;
    for (int i = threadIdx.x; i < 2048; i += 256) m = fmaxf(m, maxp[i]);
    #pragma unroll
    for (int o = 32; o >= 1; o >>= 1) m = fmaxf(m, __shfl_down(m, o, 64));
    __shared__ float red[4];
    if ((threadIdx.x & 63) == 0) red[threadIdx.x >> 6] = m;
    __syncthreads();
    if (threadIdx.x == 0)
        Mb[0] = fmaxf(fmaxf(red[0], red[1]), fmaxf(red[2], red[3]));
}

// ---------- mask(A[+I]) @ B : 32x32x16 MFMA, frag-major B, one barrier ----------
template <bool DIAG>
__global__ __launch_bounds__(256, 2) void mm_kernel(const u64* __restrict__ mask,
        const short* __restrict__ Bfrag, float* __restrict__ outp) {
    __shared__ short Bs[32768];             // 64 frags x 1KB
    const int t = threadIdx.x;
    const int mt = blockIdx.x, ks = blockIdx.y;
    const int l = t & 63, w = t >> 6;
    const int kbase = ks * KCH;

    // stage 64 KB of fragment-major B (linear, coalesced, conflict-free)
    {
        const short* src = Bfrag + (size_t)(kbase >> 4) * 2 * 512;
        #pragma unroll
        for (int r = 0; r < 16; ++r) {
            int u = t + r * 256;
            *(short8*)&Bs[u * 8] = *(const short8*)(src + (size_t)u * 8);
        }
    }
    // mask window: 2 row-sets, 64 B each (8 u64)
    const int r0 = mt * 256 + w * 32 + (l & 31);
    const u64* mp0 = mask + (size_t)r0 * NWRD + (kbase >> 6);
    const u64* mp1 = mp0 + (size_t)128 * NWRD;
    u64 mw0[8], mw1[8];
    #pragma unroll
    for (int q = 0; q < 8; ++q) { mw0[q] = mp0[q]; mw1[q] = mp1[q]; }
    __syncthreads();

    const int kh = l >> 5;
    f32x16 acc[2][2] = {};
    #pragma unroll
    for (int kt = 0; kt < KT_PER; ++kt) {
        const int sh = (((kt & 3) * 2 + kh) * 8);
        u32 b0 = (u32)(mw0[kt >> 2] >> sh) & 0xFFu;
        u32 b1 = (u32)(mw1[kt >> 2] >> sh) & 0xFFu;
        if (DIAG) {
            int kg = kbase + kt * 16 + kh * 8;
            u32 d0 = (u32)(r0 - kg);       if (d0 < 8u) b0 |= 1u << d0;
            u32 d1 = (u32)(r0 + 128 - kg); if (d1 < 8u) b1 |= 1u << d1;
        }
        short8 a0 = expand8(b0);
        short8 a1 = expand8(b1);
        short8 bf0 = *(const short8*)&Bs[(kt * 2 + 0) * 512 + l * 8];
        short8 bf1 = *(const short8*)&Bs[(kt * 2 + 1) * 512 + l * 8];
        acc[0][0] = __builtin_amdgcn_mfma_f32_32x32x16_bf16(a0, bf0, acc[0][0], 0, 0, 0);
        acc[0][1] = __builtin_amdgcn_mfma_f32_32x32x16_bf16(a0, bf1, acc[0][1], 0, 0, 0);
        acc[1][0] = __builtin_amdgcn_mfma_f32_32x32x16_bf16(a1, bf0, acc[1][0], 0, 0, 0);
        acc[1][1] = __builtin_amdgcn_mfma_f32_32x32x16_bf16(a1, bf1, acc[1][1], 0, 0, 0);
    }

    // D: col = lane&31, row = (q&3) + 8*(q>>2) + 4*(lane>>5)
    const int cc = l & 31;
    const int rq = 4 * (l >> 5);
    #pragma unroll
    for (int m = 0; m < 2; ++m) {
        #pragma unroll
        for (int ct = 0; ct < 2; ++ct) {
            #pragma unroll
            for (int q = 0; q < 16; ++q) {
                int i = mt * 256 + w * 32 + m * 128 + (q & 3) + 8 * (q >> 2) + rq;
                outp[((size_t)ks * NN + i) * 64 + ct * 32 + cc] = acc[m][ct][q];
            }
        }
    }
}

// ---------- B2 = bf16(e_j * (agg_j + bias)) in fragment-major ----------
__global__ __launch_bounds__(256) void bbuild_kernel(const float* __restrict__ aggp,
        const float* __restrict__ bias, const float* __restrict__ sjv,
        const float* __restrict__ Mb, short* __restrict__ B2f) {
    __shared__ short T[64][72];
    const int t = threadIdx.x;
    const int jb = blockIdx.x * 64;
    const int jl = t >> 2;
    const int j = jb + jl;
    const int cg = (t & 3) * 16;
    float v[16] = {};
    #pragma unroll
    for (int ks = 0; ks < KSPLIT; ++ks) {
        const float4* p = (const float4*)&aggp[((size_t)ks * NN + j) * 64 + cg];
        float4 q0 = p[0], q1 = p[1], q2 = p[2], q3 = p[3];
        v[0] += q0.x; v[1] += q0.y; v[2] += q0.z; v[3] += q0.w;
        v[4] += q1.x; v[5] += q1.y; v[6] += q1.z; v[7] += q1.w;
        v[8] += q2.x; v[9] += q2.y; v[10] += q2.z; v[11] += q2.w;
        v[12] += q3.x; v[13] += q3.y; v[14] += q3.z; v[15] += q3.w;
    }
    const float e = __expf(sjv[j] - Mb[0]);
    union { short s[16]; short8 w[2]; } pk;
    #pragma unroll
    for (int q = 0; q < 16; ++q) pk.s[q] = f2bf((v[q] + bias[cg + q]) * e);
    *(short8*)&T[jl][cg] = pk.w[0];
    *(short8*)&T[jl][cg + 8] = pk.w[1];
    __syncthreads();
    #pragma unroll
    for (int uu = 0; uu < 2; ++uu) {
        int u = t + uu * 256;
        int f = u >> 6, ln = u & 63;
        int c = (f & 1) * 32 + (ln & 31);
        int j0 = (f >> 1) * 16 + (ln >> 5) * 8;
        union { short s[8]; short8 v; } w8;
        #pragma unroll
        for (int e8 = 0; e8 < 8; ++e8) w8.s[e8] = T[j0 + e8][c];
        size_t fg = ((size_t)(jb >> 4) + (f >> 1)) * 2 + (f & 1);
        *(short8*)&B2f[fg * 512 + ln * 8] = w8.v;
    }
}

// ---------- den partials: den_i = sum_{j in mask+I} e_j ----------
__global__ __launch_bounds__(256) void den_kernel(const u64* __restrict__ mask,
        const float* __restrict__ sjv, const float* __restrict__ Mb,
        float* __restrict__ denp) {
    __shared__ float4 es4[NN / 4];
    float* es = (float*)es4;
    const float M = Mb[0];
    for (int i = threadIdx.x; i < NN; i += 256) es[i] = __expf(sjv[i] - M);
    __syncthreads();
    const int t = threadIdx.x;
    const int row = blockIdx.x * 16 + (t >> 4);
    const int cs = t & 15;
    const u64* mp = mask + (size_t)row * NWRD + cs * 8;
    float s = 0.f;
    #pragma unroll
    for (int wd = 0; wd < 8; ++wd) {
        u64 mw = mp[wd];
        const int kg = cs * 512 + wd * 64;
        u32 d = (u32)(row - kg);
        if (d < 64u) mw |= 1ull << d;     // +I
        #pragma unroll
        for (int b = 0; b < 8; ++b) {
            u32 by = (u32)(mw >> (b * 8)) & 0xFFu;
            u32 xl = ((by & 0xFu) * 0x00204081u) & 0x01010101u;
            u32 xh = (((by >> 4) & 0xFu) * 0x00204081u) & 0x01010101u;
            u32 d0 = __builtin_amdgcn_perm(0u, xl, 0x0C010C00u) * 0x3F80u;
            u32 d1 = __builtin_amdgcn_perm(0u, xl, 0x0C030C02u) * 0x3F80u;
            u32 d2 = __builtin_amdgcn_perm(0u, xh, 0x0C010C00u) * 0x3F80u;
            u32 d3 = __builtin_amdgcn_perm(0u, xh, 0x0C030C02u) * 0x3F80u;
            const float* ep = es + kg + b * 8;
            s = fmaf(__uint_as_float(d0 << 16), ep[0], s);
            s = fmaf(__uint_as_float(d0 & 0xFFFF0000u), ep[1], s);
            s = fmaf(__uint_as_float(d1 << 16), ep[2], s);
            s = fmaf(__uint_as_float(d1 & 0xFFFF0000u), ep[3], s);
            s = fmaf(__uint_as_float(d2 << 16), ep[4], s);
            s = fmaf(__uint_as_float(d2 & 0xFFFF0000u), ep[5], s);
            s = fmaf(__uint_as_float(d3 << 16), ep[6], s);
            s = fmaf(__uint_as_float(d3 & 0xFFFF0000u), ep[7], s);
        }
    }
    denp[row * 16 + cs] = s;
}

// ---------- out = relu( (sum_ks hp) / den ) ----------
__global__ __launch_bounds__(256) void final_kernel(const float* __restrict__ hp,
        const float* __restrict__ denp, float* __restrict__ out) {
    const int idx = blockIdx.x * 256 + threadIdx.x;
    const int i = idx >> 6, c = idx & 63;
    float num = 0.f;
    #pragma unroll
    for (int ks = 0; ks < KSPLIT; ++ks)
        num += hp[((size_t)ks * NN + i) * 64 + c];
    float den = 0.f;
    #pragma unroll
    for (int k = 0; k < 16; ++k) den += denp[i * 16 + k];
    float v = num / den;
    out[idx] = v > 0.f ? v : 0.f;
}

extern "C" void kernel_launch(void* const* d_in, const int* in_sizes, int n_in,
                              void* d_out, int out_size, void* d_ws, size_t ws_size,
                              hipStream_t stream) {
    const float* A    = (const float*)d_in[0];
    const float* X    = (const float*)d_in[1];
    const float* W    = (const float*)d_in[2];
    const float* bias = (const float*)d_in[3];
    const float* phi  = (const float*)d_in[4];
    float* out = (float*)d_out;

    char* ws = (char*)d_ws;
    size_t off = 0;
    auto alloc = [&](size_t bytes) -> void* {
        void* p = ws + off;
        off += (bytes + 255) & ~(size_t)255;
        return p;
    };
    u8*    m8   = (u8*)alloc((size_t)NN * NB);
    short* XWf  = (short*)alloc((size_t)FOUT * NN * 2);
    float* y    = (float*)alloc((size_t)NN * 4);
    float* cb   = (float*)alloc(256);
    float* sjv  = (float*)alloc((size_t)NN * 4);
    float* maxp = (float*)alloc(2048 * 4);
    float* Mb   = (float*)alloc(256);
    float* aggp = (float*)alloc((size_t)KSPLIT * NN * 64 * 4);
    short* B2f  = (short*)alloc((size_t)FOUT * NN * 2);
    float* denp = (float*)alloc((size_t)NN * 16 * 4);
    float* hp   = (float*)alloc((size_t)KSPLIT * NN * 64 * 4);

    xw_kernel<<<NN / 64, 256, 0, stream>>>(X, W, bias, phi, XWf, y, cb);
    mask_kernel<<<NN / 4, 256, 0, stream>>>(A, y, cb, m8, sjv, maxp);
    maxfin_kernel<<<1, 256, 0, stream>>>(maxp, Mb);
    mm_kernel<false><<<dim3(NN / 256, KSPLIT), 256, 0, stream>>>(
        (const u64*)m8, XWf, aggp);
    bbuild_kernel<<<NN / 64, 256, 0, stream>>>(aggp, bias, sjv, Mb, B2f);
    den_kernel<<<NN / 16, 256, 0, stream>>>((const u64*)m8, sjv, Mb, denp);
    mm_kernel<true><<<dim3(NN / 256, KSPLIT), 256, 0, stream>>>(
        (const u64*)m8, B2f, hp);
    final_kernel<<<NN * 64 / 256, 256, 0, stream>>>(hp, denp, out);
}

// Round 5
// 147.542 us; speedup vs baseline: 1.7474x; 1.1954x over previous
//
#include <hip/hip_runtime.h>
#include <hip/hip_bf16.h>

#define NN 8192
#define FIN 128
#define FOUT 64
#define NWRD (NN / 64)       // 128 u64 words per mask row
#define NB (NN / 8)          // 1024 mask bytes per row

typedef __attribute__((ext_vector_type(8))) short short8;
typedef __attribute__((ext_vector_type(16))) float f32x16;
typedef unsigned int u32;
typedef unsigned char u8;
typedef unsigned long long u64;

static __device__ __forceinline__ short f2bf(float f) {
    union { __hip_bfloat16 h; short s; } u;
    u.h = __float2bfloat16(f);
    return u.s;
}

// one mask byte (8 bits) -> 8 bf16 {0,1.0} packed in short8
static __device__ __forceinline__ short8 expand8(u32 b) {
    u32 xl = ((b & 0xFu) * 0x00204081u) & 0x01010101u;
    u32 xh = (((b >> 4) & 0xFu) * 0x00204081u) & 0x01010101u;
    u32 d0 = __builtin_amdgcn_perm(0u, xl, 0x0C010C00u) * 0x3F80u;
    u32 d1 = __builtin_amdgcn_perm(0u, xl, 0x0C030C02u) * 0x3F80u;
    u32 d2 = __builtin_amdgcn_perm(0u, xh, 0x0C010C00u) * 0x3F80u;
    u32 d3 = __builtin_amdgcn_perm(0u, xh, 0x0C030C02u) * 0x3F80u;
    union { u32 u[4]; short8 v; } r;
    r.u[0] = d0; r.u[1] = d1; r.u[2] = d2; r.u[3] = d3;
    return r.v;
}

// ---------- XW (no bias) -> fragment-major bf16 + y = XW@phi_j + cb ----------
__global__ __launch_bounds__(256) void xw_kernel(const float* __restrict__ X,
        const float* __restrict__ W, const float* __restrict__ bias,
        const float* __restrict__ phi, short* __restrict__ XWf,
        float* __restrict__ y, float* __restrict__ cb) {
    __shared__ float Xs[64][FIN + 1];
    __shared__ short T[64][72];     // [node j][col c] bf16, padded
    __shared__ float yp[4][64];
    const int t = threadIdx.x;
    const int jb = blockIdx.x * 64;
    for (int u = t; u < 64 * FIN; u += 256) {
        int r = u >> 7, k = u & (FIN - 1);
        Xs[r][k] = X[(size_t)(jb + r) * FIN + k];
    }
    __syncthreads();
    const int j = t & 63;
    const int cg = t >> 6;
    float acc[16] = {};
    for (int k = 0; k < FIN; ++k) {
        float x = Xs[j][k];
        #pragma unroll
        for (int q = 0; q < 16; ++q)
            acc[q] = fmaf(x, W[k * FOUT + cg * 16 + q], acc[q]);
    }
    float ys = 0.f;
    union { short s[16]; short8 v[2]; } pk;
    #pragma unroll
    for (int q = 0; q < 16; ++q) {
        ys = fmaf(acc[q], phi[FOUT + cg * 16 + q], ys);
        pk.s[q] = f2bf(acc[q]);
    }
    *(short8*)&T[j][cg * 16] = pk.v[0];
    *(short8*)&T[j][cg * 16 + 8] = pk.v[1];
    yp[cg][j] = ys;
    __syncthreads();
    if (t < 64) y[jb + t] = yp[0][t] + yp[1][t] + yp[2][t] + yp[3][t];
    if (blockIdx.x == 0 && t == 0) {
        float s = 0.f;
        for (int c = 0; c < FOUT; ++c) s = fmaf(bias[c], phi[FOUT + c], s);
        cb[0] = s;
    }
    // fragment-major write: frag fi = ktile*2 + colgroup, lane l: B[k=(l>>5)*8+e][c=(l&31)]
    #pragma unroll
    for (int uu = 0; uu < 2; ++uu) {
        int u = t + uu * 256;
        int f = u >> 6, ln = u & 63;
        int c = (f & 1) * 32 + (ln & 31);
        int j0 = (f >> 1) * 16 + (ln >> 5) * 8;
        union { short s[8]; short8 v; } w8;
        #pragma unroll
        for (int e = 0; e < 8; ++e) w8.s[e] = T[j0 + e][c];
        size_t fg = ((size_t)(jb >> 4) + (f >> 1)) * 2 + (f & 1);
        *(short8*)&XWf[fg * 512 + ln * 8] = w8.v;
    }
}

// ---------- A -> bitmask bytes; fused exact sj_i = A@y + cb; block max ----------
__global__ __launch_bounds__(256) void mask_kernel(const float* __restrict__ A,
        const float* __restrict__ y, const float* __restrict__ cb,
        u8* __restrict__ m8, float* __restrict__ sjv, float* __restrict__ maxp) {
    __shared__ float4 ys4[NN / 4];
    const float* ysp = (const float*)ys4;
    for (int i = threadIdx.x; i < NN / 4; i += 256)
        ys4[i] = ((const float4*)y)[i];
    __syncthreads();
    const int t = threadIdx.x;
    const int row = blockIdx.x * 4 + (t >> 6);
    const int l = t & 63;
    const float* ar = A + (size_t)row * NN + l * 8;
    u8* mr = m8 + (size_t)row * NB + l;
    float s = 0.f;
    #pragma unroll 2
    for (int kc = 0; kc < NN; kc += 512) {
        float4 a = *(const float4*)(ar + kc);
        float4 b = *(const float4*)(ar + kc + 4);
        float4 y0 = *(const float4*)(ysp + kc + l * 8);
        float4 y1 = *(const float4*)(ysp + kc + l * 8 + 4);
        s = fmaf(a.x, y0.x, s); s = fmaf(a.y, y0.y, s);
        s = fmaf(a.z, y0.z, s); s = fmaf(a.w, y0.w, s);
        s = fmaf(b.x, y1.x, s); s = fmaf(b.y, y1.y, s);
        s = fmaf(b.z, y1.z, s); s = fmaf(b.w, y1.w, s);
        u32 x0 = __float_as_uint(a.x), x1 = __float_as_uint(a.y);
        u32 x2 = __float_as_uint(a.z), x3 = __float_as_uint(a.w);
        u32 x4 = __float_as_uint(b.x), x5 = __float_as_uint(b.y);
        u32 x6 = __float_as_uint(b.z), x7 = __float_as_uint(b.w);
        u32 ylo = __builtin_amdgcn_perm(x1, x0, 0x0C0C0703u) |
                  __builtin_amdgcn_perm(x3, x2, 0x07030C0Cu);
        u32 yhi = __builtin_amdgcn_perm(x5, x4, 0x0C0C0703u) |
                  __builtin_amdgcn_perm(x7, x6, 0x07030C0Cu);
        u32 nlo = (((ylo >> 5) & 0x01010101u) * 0x01020408u) >> 24;
        u32 nhi = (((yhi >> 5) & 0x01010101u) * 0x01020408u) >> 24;
        mr[kc >> 3] = (u8)(nlo | (nhi << 4));
    }
    #pragma unroll
    for (int o = 32; o >= 1; o >>= 1) s += __shfl_down(s, o, 64);
    __shared__ float red[4];
    float sj = s + cb[0];
    if (l == 0) { sjv[row] = sj; red[t >> 6] = sj; }
    __syncthreads();
    if (t == 0)
        maxp[blockIdx.x] = fmaxf(fmaxf(red[0], red[1]), fmaxf(red[2], red[3]));
}

__global__ __launch_bounds__(256) void maxfin_kernel(const float* __restrict__ maxp,
                                                     float* __restrict__ Mb) {
    float m = -3.0e38f;
    for (int i = threadIdx.x; i < 2048; i += 256) m = fmaxf(m, maxp[i]);
    #pragma unroll
    for (int o = 32; o >= 1; o >>= 1) m = fmaxf(m, __shfl_down(m, o, 64));
    __shared__ float red[4];
    if ((threadIdx.x & 63) == 0) red[threadIdx.x >> 6] = m;
    __syncthreads();
    if (threadIdx.x == 0)
        Mb[0] = fmaxf(fmaxf(red[0], red[1]), fmaxf(red[2], red[3]));
}

// ---------- mask(A[+I]) @ B : full-K per block, no split-K partials ----------
// 256 blocks x 32 rows; 8 waves each own K=1024; B-frags global->VGPR (L2-hit).
template <bool DIAG>
__global__ __launch_bounds__(512) void mm_kernel(const u64* __restrict__ mask,
        const short* __restrict__ Bfrag, float* __restrict__ outv) {
    __shared__ float red[8][2048];
    const int t = threadIdx.x;
    const int w = t >> 6;          // wave 0..7
    const int l = t & 63;
    const int brow = blockIdx.x * 32;
    const int r0 = brow + (l & 31);
    const int kh = l >> 5;
    const int k0 = w * 1024;       // wave's K-chunk base

    // mask window for row r0, k in [k0, k0+1024): 128 bytes = 16 u64, in VGPRs
    const u64* mp = mask + (size_t)r0 * NWRD + (k0 >> 6);
    u64 mw[16];
    #pragma unroll
    for (int q = 0; q < 16; ++q) mw[q] = mp[q];

    f32x16 acc0 = {}, acc1 = {};
    const short* bp = Bfrag + (size_t)(k0 >> 4) * 2 * 512 + l * 8;

    // 64 k-tiles of 16, software pipeline depth 4
    short8 f0a, f1a, f0b, f1b, f0c, f1c, f0d, f1d;
    f0a = *(const short8*)(bp + 0 * 512);  f1a = *(const short8*)(bp + 1 * 512);
    f0b = *(const short8*)(bp + 2 * 512);  f1b = *(const short8*)(bp + 3 * 512);
    f0c = *(const short8*)(bp + 4 * 512);  f1c = *(const short8*)(bp + 5 * 512);
    f0d = *(const short8*)(bp + 6 * 512);  f1d = *(const short8*)(bp + 7 * 512);

    #pragma unroll
    for (int kt4 = 0; kt4 < 16; ++kt4) {
        #pragma unroll
        for (int pp = 0; pp < 4; ++pp) {
            const int kt = kt4 * 4 + pp;
            const int bidx = kt * 2 + kh;
            u32 b = (u32)(mw[bidx >> 3] >> ((bidx & 7) * 8)) & 0xFFu;
            if (DIAG) {
                u32 d = (u32)(r0 - (k0 + kt * 16 + kh * 8));
                if (d < 8u) b |= 1u << d;
            }
            short8 a = expand8(b);
            short8 bf0 = (pp == 0) ? f0a : (pp == 1) ? f0b : (pp == 2) ? f0c : f0d;
            short8 bf1 = (pp == 0) ? f1a : (pp == 1) ? f1b : (pp == 2) ? f1c : f1d;
            acc0 = __builtin_amdgcn_mfma_f32_32x32x16_bf16(a, bf0, acc0, 0, 0, 0);
            acc1 = __builtin_amdgcn_mfma_f32_32x32x16_bf16(a, bf1, acc1, 0, 0, 0);
            if (kt + 4 < 64) {
                short8 n0 = *(const short8*)(bp + ((kt + 4) * 2 + 0) * 512);
                short8 n1 = *(const short8*)(bp + ((kt + 4) * 2 + 1) * 512);
                if (pp == 0) { f0a = n0; f1a = n1; }
                else if (pp == 1) { f0b = n0; f1b = n1; }
                else if (pp == 2) { f0c = n0; f1c = n1; }
                else { f0d = n0; f1d = n1; }
            }
        }
    }

    // cross-wave reduce in LDS: D layout col=lane&31, row=(q&3)+8*(q>>2)+4*(lane>>5)
    const int cc = l & 31;
    const int rq4 = 4 * (l >> 5);
    #pragma unroll
    for (int q = 0; q < 16; ++q) {
        int row = (q & 3) + 8 * (q >> 2) + rq4;
        red[w][row * 64 + cc] = acc0[q];
        red[w][row * 64 + 32 + cc] = acc1[q];
    }
    __syncthreads();
    float4 s = {0.f, 0.f, 0.f, 0.f};
    #pragma unroll
    for (int ww = 0; ww < 8; ++ww) {
        float4 v = *(const float4*)&red[ww][t * 4];
        s.x += v.x; s.y += v.y; s.z += v.z; s.w += v.w;
    }
    *(float4*)&outv[(size_t)brow * 64 + t * 4] = s;
}

// ---------- B2 = bf16(e_j * (agg_j + bias)) in fragment-major ----------
__global__ __launch_bounds__(256) void bbuild_kernel(const float* __restrict__ aggr,
        const float* __restrict__ bias, const float* __restrict__ sjv,
        const float* __restrict__ Mb, short* __restrict__ B2f) {
    __shared__ short T[64][72];
    const int t = threadIdx.x;
    const int jb = blockIdx.x * 64;
    const int jl = t >> 2;
    const int j = jb + jl;
    const int cg = (t & 3) * 16;
    const float4* p = (const float4*)&aggr[(size_t)j * 64 + cg];
    float4 q0 = p[0], q1 = p[1], q2 = p[2], q3 = p[3];
    float v[16] = {q0.x, q0.y, q0.z, q0.w, q1.x, q1.y, q1.z, q1.w,
                   q2.x, q2.y, q2.z, q2.w, q3.x, q3.y, q3.z, q3.w};
    const float e = __expf(sjv[j] - Mb[0]);
    union { short s[16]; short8 w[2]; } pk;
    #pragma unroll
    for (int q = 0; q < 16; ++q) pk.s[q] = f2bf((v[q] + bias[cg + q]) * e);
    *(short8*)&T[jl][cg] = pk.w[0];
    *(short8*)&T[jl][cg + 8] = pk.w[1];
    __syncthreads();
    #pragma unroll
    for (int uu = 0; uu < 2; ++uu) {
        int u = t + uu * 256;
        int f = u >> 6, ln = u & 63;
        int c = (f & 1) * 32 + (ln & 31);
        int j0 = (f >> 1) * 16 + (ln >> 5) * 8;
        union { short s[8]; short8 v; } w8;
        #pragma unroll
        for (int e8 = 0; e8 < 8; ++e8) w8.s[e8] = T[j0 + e8][c];
        size_t fg = ((size_t)(jb >> 4) + (f >> 1)) * 2 + (f & 1);
        *(short8*)&B2f[fg * 512 + ln * 8] = w8.v;
    }
}

// ---------- den_i = sum_{j in mask+I} e_j  (bit-expand FMA, reduced) ----------
__global__ __launch_bounds__(256) void den_kernel(const u64* __restrict__ mask,
        const float* __restrict__ sjv, const float* __restrict__ Mb,
        float* __restrict__ den) {
    __shared__ float4 es4[NN / 4];
    float* es = (float*)es4;
    const float M = Mb[0];
    for (int i = threadIdx.x; i < NN; i += 256) es[i] = __expf(sjv[i] - M);
    __syncthreads();
    const int t = threadIdx.x;
    const int row = blockIdx.x * 16 + (t >> 4);
    const int cs = t & 15;
    const u64* mp = mask + (size_t)row * NWRD + cs * 8;
    float s = 0.f;
    #pragma unroll
    for (int wd = 0; wd < 8; ++wd) {
        u64 mw = mp[wd];
        const int kg = cs * 512 + wd * 64;
        u32 d = (u32)(row - kg);
        if (d < 64u) mw |= 1ull << d;     // +I
        #pragma unroll
        for (int b = 0; b < 8; ++b) {
            u32 by = (u32)(mw >> (b * 8)) & 0xFFu;
            u32 xl = ((by & 0xFu) * 0x00204081u) & 0x01010101u;
            u32 xh = (((by >> 4) & 0xFu) * 0x00204081u) & 0x01010101u;
            u32 d0 = __builtin_amdgcn_perm(0u, xl, 0x0C010C00u) * 0x3F80u;
            u32 d1 = __builtin_amdgcn_perm(0u, xl, 0x0C030C02u) * 0x3F80u;
            u32 d2 = __builtin_amdgcn_perm(0u, xh, 0x0C010C00u) * 0x3F80u;
            u32 d3 = __builtin_amdgcn_perm(0u, xh, 0x0C030C02u) * 0x3F80u;
            const float* ep = es + kg + b * 8;
            s = fmaf(__uint_as_float(d0 << 16), ep[0], s);
            s = fmaf(__uint_as_float(d0 & 0xFFFF0000u), ep[1], s);
            s = fmaf(__uint_as_float(d1 << 16), ep[2], s);
            s = fmaf(__uint_as_float(d1 & 0xFFFF0000u), ep[3], s);
            s = fmaf(__uint_as_float(d2 << 16), ep[4], s);
            s = fmaf(__uint_as_float(d2 & 0xFFFF0000u), ep[5], s);
            s = fmaf(__uint_as_float(d3 << 16), ep[6], s);
            s = fmaf(__uint_as_float(d3 & 0xFFFF0000u), ep[7], s);
        }
    }
    // reduce the 16 k-slices within the 16-lane group
    #pragma unroll
    for (int o = 8; o >= 1; o >>= 1) s += __shfl_xor(s, o, 64);
    if (cs == 0) den[row] = s;
}

// ---------- out = relu( h / den ) ----------
__global__ __launch_bounds__(256) void final_kernel(const float* __restrict__ h,
        const float* __restrict__ den, float* __restrict__ out) {
    const int idx = blockIdx.x * 256 + threadIdx.x;
    const int i = idx >> 6;
    float v = h[idx] / den[i];
    out[idx] = v > 0.f ? v : 0.f;
}

extern "C" void kernel_launch(void* const* d_in, const int* in_sizes, int n_in,
                              void* d_out, int out_size, void* d_ws, size_t ws_size,
                              hipStream_t stream) {
    const float* A    = (const float*)d_in[0];
    const float* X    = (const float*)d_in[1];
    const float* W    = (const float*)d_in[2];
    const float* bias = (const float*)d_in[3];
    const float* phi  = (const float*)d_in[4];
    float* out = (float*)d_out;

    char* ws = (char*)d_ws;
    size_t off = 0;
    auto alloc = [&](size_t bytes) -> void* {
        void* p = ws + off;
        off += (bytes + 255) & ~(size_t)255;
        return p;
    };
    u8*    m8   = (u8*)alloc((size_t)NN * NB);
    short* XWf  = (short*)alloc((size_t)FOUT * NN * 2);
    float* y    = (float*)alloc((size_t)NN * 4);
    float* cb   = (float*)alloc(256);
    float* sjv  = (float*)alloc((size_t)NN * 4);
    float* maxp = (float*)alloc(2048 * 4);
    float* Mb   = (float*)alloc(256);
    float* aggr = (float*)alloc((size_t)NN * FOUT * 4);
    short* B2f  = (short*)alloc((size_t)FOUT * NN * 2);
    float* den  = (float*)alloc((size_t)NN * 4);
    float* h    = (float*)alloc((size_t)NN * FOUT * 4);

    xw_kernel<<<NN / 64, 256, 0, stream>>>(X, W, bias, phi, XWf, y, cb);
    mask_kernel<<<NN / 4, 256, 0, stream>>>(A, y, cb, m8, sjv, maxp);
    maxfin_kernel<<<1, 256, 0, stream>>>(maxp, Mb);
    mm_kernel<false><<<NN / 32, 512, 0, stream>>>((const u64*)m8, XWf, aggr);
    bbuild_kernel<<<NN / 64, 256, 0, stream>>>(aggr, bias, sjv, Mb, B2f);
    den_kernel<<<NN / 16, 256, 0, stream>>>((const u64*)m8, sjv, Mb, den);
    mm_kernel<true><<<NN / 32, 512, 0, stream>>>((const u64*)m8, B2f, h);
    final_kernel<<<NN * 64 / 256, 256, 0, stream>>>(h, den, out);
}